// Round 5
// baseline (349.144 us; speedup 1.0000x reference)
//
#include <hip/hip_runtime.h>
#include <math.h>

#define TOT_S   13294
#define NBATCH  2
#define CCH     512
#define MHEAD   8
#define PITCH   40   // LDS row pitch in bf16 elems (32 + 8 pad -> 80B)

typedef short     short8  __attribute__((ext_vector_type(8)));
typedef float     f32x4   __attribute__((ext_vector_type(4)));
typedef unsigned short u16x8 __attribute__((ext_vector_type(8)));
typedef unsigned short u16x4 __attribute__((ext_vector_type(4)));

__device__ __forceinline__ unsigned short f2bf(float f) {
    union { float f; unsigned int u; } v; v.f = f;
    unsigned int r = v.u + 0x7fffu + ((v.u >> 16) & 1u);   // RNE
    return (unsigned short)(r >> 16);
}
__device__ __forceinline__ float bf2f(unsigned short h) {
    union { unsigned int u; float f; } v; v.u = ((unsigned int)h) << 16;
    return v.f;
}

// ---------------------------------------------------------------------------
__global__ void cast_f32_bf16(const float* __restrict__ src,
                              unsigned short* __restrict__ dst, int n4)
{
    const int i = blockIdx.x * blockDim.x + threadIdx.x;
    if (i < n4) {
        const float4 v = *(const float4*)(src + (size_t)i * 4);
        u16x4 o;
        o[0] = f2bf(v.x); o[1] = f2bf(v.y); o[2] = f2bf(v.z); o[3] = f2bf(v.w);
        *(u16x4*)(dst + (size_t)i * 4) = o;
    }
}

// ---------------------------------------------------------------------------
// MFMA GEMM 1 with FUSED transpose-cast staging of B from f32 (C,S) layout.
// value_b[n][s][o] = bf16((sum_c Wv[o][c]*x[c][s] + bv[o])*msk)
// B-staging: thread (kr=tid&7, sq=tid>>3) loads a 4k x 4s f32 micro-tile of
// x, converts to bf16, writes 4 transposed u16x4 rows into Al[s][k].
// ---------------------------------------------------------------------------
__global__ __launch_bounds__(256)
void gemm_value_mfma(const unsigned short* __restrict__ Wb,   // (512,512) bf16
                     const float* __restrict__ X,             // (N,512,S) f32
                     const float* __restrict__ bv,
                     const unsigned char* __restrict__ mask,
                     unsigned short* __restrict__ valb)       // (N,S,512) bf16
{
    __shared__ unsigned short Wl[128 * PITCH];
    __shared__ unsigned short Al[128 * PITCH];
    const int n  = blockIdx.z;
    const int ob = blockIdx.y * 128;
    const int sb = blockIdx.x * 128;
    const int tid = threadIdx.x;

    // A (weights) staging
    const int r   = tid >> 1;
    const int seg = (tid & 1) * 16;
    const unsigned short* wsrc = Wb + ((size_t)(ob + r)) * CCH + seg;
    unsigned short* wdst = &Wl[r * PITCH + seg];

    // B (activation) staging: fused transpose-cast
    const int kr = tid & 7;          // k-quad: k = kr*4 .. +3
    const int sq = tid >> 3;         // s-quad: s = sq*4 .. +3
    const int sl = sq * 4;
    const int sg = sb + sl;
    const float* Xn = X + (size_t)n * CCH * TOT_S;
    const bool fast = (sg + 3 < TOT_S);

    const int wave = tid >> 6, lane = tid & 63;
    const int m0 = (wave & 1) * 64, n0 = (wave >> 1) * 64;
    const int row16 = lane & 15, q = lane >> 4;

    u16x8 w0 = *(const u16x8*)(wsrc);
    u16x8 w1 = *(const u16x8*)(wsrc + 8);
    f32x4 xv[4];
#pragma unroll
    for (int j = 0; j < 4; ++j) {
        const size_t roff = (size_t)(kr * 4 + j) * TOT_S;
        if (fast) xv[j] = *(const f32x4*)(Xn + roff + sg);
        else {
#pragma unroll
            for (int i = 0; i < 4; ++i)
                xv[j][i] = Xn[roff + min(sg + i, TOT_S - 1)];
        }
    }

    f32x4 acc[4][4] = {};
    for (int k0 = 0; k0 < CCH; k0 += 32) {
        *(u16x8*)wdst = w0; *(u16x8*)(wdst + 8) = w1;
#pragma unroll
        for (int i = 0; i < 4; ++i) {
            u16x4 t;
            t[0] = f2bf(xv[0][i]); t[1] = f2bf(xv[1][i]);
            t[2] = f2bf(xv[2][i]); t[3] = f2bf(xv[3][i]);
            *(u16x4*)&Al[(sl + i) * PITCH + kr * 4] = t;
        }
        __syncthreads();
        if (k0 + 32 < CCH) {
            w0 = *(const u16x8*)(wsrc + k0 + 32);
            w1 = *(const u16x8*)(wsrc + k0 + 40);
#pragma unroll
            for (int j = 0; j < 4; ++j) {
                const size_t roff = (size_t)(k0 + 32 + kr * 4 + j) * TOT_S;
                if (fast) xv[j] = *(const f32x4*)(Xn + roff + sg);
                else {
#pragma unroll
                    for (int i = 0; i < 4; ++i)
                        xv[j][i] = Xn[roff + min(sg + i, TOT_S - 1)];
                }
            }
        }
        short8 af[4], bfr[4];
#pragma unroll
        for (int mt = 0; mt < 4; ++mt)
            af[mt] = *(const short8*)&Wl[(m0 + mt * 16 + row16) * PITCH + q * 8];
#pragma unroll
        for (int nt = 0; nt < 4; ++nt)
            bfr[nt] = *(const short8*)&Al[(n0 + nt * 16 + row16) * PITCH + q * 8];
#pragma unroll
        for (int mt = 0; mt < 4; ++mt)
#pragma unroll
            for (int nt = 0; nt < 4; ++nt)
                acc[mt][nt] = __builtin_amdgcn_mfma_f32_16x16x32_bf16(
                    af[mt], bfr[nt], acc[mt][nt], 0, 0, 0);
        __syncthreads();
    }

#pragma unroll
    for (int nt = 0; nt < 4; ++nt) {
        const int s = sb + n0 + nt * 16 + row16;
        if (s >= TOT_S) continue;
        const float msk = mask[(size_t)n * TOT_S + s] ? 0.f : 1.f;
        unsigned short* orow = valb + ((size_t)n * TOT_S + s) * CCH + ob + m0;
#pragma unroll
        for (int mt = 0; mt < 4; ++mt) {
            const f32x4 bvv = *(const f32x4*)(bv + ob + m0 + mt * 16 + q * 4);
            const f32x4 a = acc[mt][nt];
            u16x4 ov;
            ov[0] = f2bf((a[0] + bvv[0]) * msk);
            ov[1] = f2bf((a[1] + bvv[1]) * msk);
            ov[2] = f2bf((a[2] + bvv[2]) * msk);
            ov[3] = f2bf((a[3] + bvv[3]) * msk);
            *(u16x4*)(orow + mt * 16 + q * 4) = ov;
        }
    }
}

// ---------------------------------------------------------------------------
// MFMA GEMM 2 (offsets+logits) with FUSED transpose-cast of (mask?0:x+pos).
// ---------------------------------------------------------------------------
__global__ __launch_bounds__(256)
void gemm_offw_mfma(const unsigned short* __restrict__ Wlb,
                    const unsigned short* __restrict__ Wwb,
                    const float* __restrict__ bloc, const float* __restrict__ bw,
                    const float* __restrict__ X, const float* __restrict__ POS,
                    const unsigned char* __restrict__ mask,
                    float* __restrict__ offw)
{
    __shared__ unsigned short Wl[128 * PITCH];
    __shared__ unsigned short Al[128 * PITCH];
    const int n  = blockIdx.z;
    const int sb = blockIdx.x * 128;
    const int tid = threadIdx.x;

    const int r   = tid >> 1;
    const int seg = (tid & 1) * 16;
    const bool wzero = (r >= 96);
    const unsigned short* wsrc =
        (r < 64) ? (Wlb + (size_t)r * CCH + seg)
                 : (Wwb + (size_t)((r < 96 ? r : 95) - 64) * CCH + seg);
    unsigned short* wdst = &Wl[r * PITCH + seg];

    const int kr = tid & 7;
    const int sq = tid >> 3;
    const int sl = sq * 4;
    const int sg = sb + sl;
    const float* Xn = X   + (size_t)n * CCH * TOT_S;
    const float* Pn = POS + (size_t)n * CCH * TOT_S;
    const bool fast = (sg + 3 < TOT_S);
    float mkf[4];
#pragma unroll
    for (int i = 0; i < 4; ++i)
        mkf[i] = mask[(size_t)n * TOT_S + min(sg + i, TOT_S - 1)] ? 0.f : 1.f;

    const int wave = tid >> 6, lane = tid & 63;
    const int m0 = (wave & 1) * 64, n0 = (wave >> 1) * 64;
    const int row16 = lane & 15, q = lane >> 4;

    u16x8 w0 = {}, w1 = {};
    if (!wzero) { w0 = *(const u16x8*)(wsrc); w1 = *(const u16x8*)(wsrc + 8); }
    f32x4 xv[4];
#pragma unroll
    for (int j = 0; j < 4; ++j) {
        const size_t roff = (size_t)(kr * 4 + j) * TOT_S;
        if (fast) {
            const f32x4 a = *(const f32x4*)(Xn + roff + sg);
            const f32x4 b = *(const f32x4*)(Pn + roff + sg);
#pragma unroll
            for (int i = 0; i < 4; ++i) xv[j][i] = (a[i] + b[i]) * mkf[i];
        } else {
#pragma unroll
            for (int i = 0; i < 4; ++i) {
                const int si = min(sg + i, TOT_S - 1);
                xv[j][i] = (Xn[roff + si] + Pn[roff + si]) * mkf[i];
            }
        }
    }

    f32x4 acc[4][4] = {};
    for (int k0 = 0; k0 < CCH; k0 += 32) {
        *(u16x8*)wdst = w0; *(u16x8*)(wdst + 8) = w1;
#pragma unroll
        for (int i = 0; i < 4; ++i) {
            u16x4 t;
            t[0] = f2bf(xv[0][i]); t[1] = f2bf(xv[1][i]);
            t[2] = f2bf(xv[2][i]); t[3] = f2bf(xv[3][i]);
            *(u16x4*)&Al[(sl + i) * PITCH + kr * 4] = t;
        }
        __syncthreads();
        if (k0 + 32 < CCH) {
            if (!wzero) {
                w0 = *(const u16x8*)(wsrc + k0 + 32);
                w1 = *(const u16x8*)(wsrc + k0 + 40);
            }
#pragma unroll
            for (int j = 0; j < 4; ++j) {
                const size_t roff = (size_t)(k0 + 32 + kr * 4 + j) * TOT_S;
                if (fast) {
                    const f32x4 a = *(const f32x4*)(Xn + roff + sg);
                    const f32x4 b = *(const f32x4*)(Pn + roff + sg);
#pragma unroll
                    for (int i = 0; i < 4; ++i) xv[j][i] = (a[i] + b[i]) * mkf[i];
                } else {
#pragma unroll
                    for (int i = 0; i < 4; ++i) {
                        const int si = min(sg + i, TOT_S - 1);
                        xv[j][i] = (Xn[roff + si] + Pn[roff + si]) * mkf[i];
                    }
                }
            }
        }
        short8 af[4], bfr[4];
#pragma unroll
        for (int mt = 0; mt < 4; ++mt)
            af[mt] = *(const short8*)&Wl[(m0 + mt * 16 + row16) * PITCH + q * 8];
#pragma unroll
        for (int nt = 0; nt < 4; ++nt)
            bfr[nt] = *(const short8*)&Al[(n0 + nt * 16 + row16) * PITCH + q * 8];
#pragma unroll
        for (int mt = 0; mt < 4; ++mt)
#pragma unroll
            for (int nt = 0; nt < 4; ++nt)
                acc[mt][nt] = __builtin_amdgcn_mfma_f32_16x16x32_bf16(
                    af[mt], bfr[nt], acc[mt][nt], 0, 0, 0);
        __syncthreads();
    }

#pragma unroll
    for (int nt = 0; nt < 4; ++nt) {
        const int s = sb + n0 + nt * 16 + row16;
        if (s >= TOT_S) continue;
        float* orow = offw + ((size_t)n * TOT_S + s) * 96;
#pragma unroll
        for (int mt = 0; mt < 4; ++mt) {
            const int o = m0 + mt * 16 + q * 4;
            if (o < 96) {
                const float* bsrc = (o < 64) ? (bloc + o) : (bw + o - 64);
                const f32x4 bb = *(const f32x4*)bsrc;
                f32x4 v = acc[mt][nt];
                v[0] += bb[0]; v[1] += bb[1]; v[2] += bb[2]; v[3] += bb[3];
                *(f32x4*)(orow + o) = v;
            }
        }
    }
}

// ---------------------------------------------------------------------------
// Sampling: one wave per (n,s). lane -> head m = lane>>3, c = lane*8..+8.
// ---------------------------------------------------------------------------
__global__ __launch_bounds__(256)
void sample_attn(const unsigned short* __restrict__ value,  // (N,S,512) bf16
                 const float* __restrict__ offw,            // (N,S,96)
                 const float* __restrict__ vsizes,
                 const float* __restrict__ vscales,
                 unsigned short* __restrict__ samp)         // (N,S,512) bf16
{
    const int lane = threadIdx.x;
    const int item = blockIdx.x * blockDim.y + threadIdx.y;
    const int total = NBATCH * TOT_S;
    if (item >= total) return;
    const int s = item % TOT_S;
    const int n = item / TOT_S;
    const int m = lane >> 3;

    int lvl; float prex, prey;
    if (s < 10000)      { lvl = 0; const int l = s;         const int qq = l / 100; prey = qq + 0.5f; prex = (l - qq * 100) + 0.5f; }
    else if (s < 12500) { lvl = 1; const int l = s - 10000; const int qq = l / 50;  prey = qq + 0.5f; prex = (l - qq * 50)  + 0.5f; }
    else if (s < 13125) { lvl = 2; const int l = s - 12500; const int qq = l / 25;  prey = qq + 0.5f; prex = (l - qq * 25)  + 0.5f; }
    else                { lvl = 3; const int l = s - 13125; const int qq = l / 13;  prey = qq + 0.5f; prex = (l - qq * 13)  + 0.5f; }

    const float* ow = offw + ((size_t)n * TOT_S + s) * 96;

    const float w0 = ow[64 + m * 4 + 0], w1 = ow[64 + m * 4 + 1];
    const float w2 = ow[64 + m * 4 + 2], w3 = ow[64 + m * 4 + 3];
    const float mx = fmaxf(fmaxf(w0, w1), fmaxf(w2, w3));
    const float e0 = expf(w0 - mx), e1 = expf(w1 - mx), e2 = expf(w2 - mx), e3 = expf(w3 - mx);
    const float inv = 1.f / (e0 + e1 + e2 + e3);
    const float wgt[4] = { e0 * inv, e1 * inv, e2 * inv, e3 * inv };

    const int HS[4]  = { 100, 50, 25, 13 };
    const int WS[4]  = { 100, 50, 25, 13 };
    const int CUR[4] = { 0, 10000, 12500, 13125 };

    const float invsx = 1.f / vsizes[((n * 4) + lvl) * 2 + 0];
    const float invsy = 1.f / vsizes[((n * 4) + lvl) * 2 + 1];
    const unsigned short* vbase = value + (size_t)n * TOT_S * CCH + lane * 8;

    float acc[8] = {};
#pragma unroll
    for (int f = 0; f < 4; ++f) {
        const float offx = ow[(m * 4 + f) * 2 + 0];
        const float offy = ow[(m * 4 + f) * 2 + 1];
        const float scx = 2.f * vscales[((n * 4) + f) * 2 + 0] * invsx;
        const float scy = 2.f * vscales[((n * 4) + f) * 2 + 1] * invsy;
        const int Wf = WS[f], Hf = HS[f], cf = CUR[f];
        const float xi = (offx + prex) * scx * (Wf * 0.5f) - 0.5f;
        const float yi = (offy + prey) * scy * (Hf * 0.5f) - 0.5f;
        const float x0f = floorf(xi), y0f = floorf(yi);
        const float wx1 = xi - x0f, wy1 = yi - y0f;
        const float wx0 = 1.f - wx1, wy0 = 1.f - wy1;
        const int x0 = (int)x0f, y0 = (int)y0f;
        const bool xin0 = (x0 >= 0) && (x0 < Wf);
        const bool xin1 = (x0 + 1 >= 0) && (x0 + 1 < Wf);
        const bool yin0 = (y0 >= 0) && (y0 < Hf);
        const bool yin1 = (y0 + 1 >= 0) && (y0 + 1 < Hf);
        const float cw00 = (xin0 && yin0) ? wgt[f] * wx0 * wy0 : 0.f;
        const float cw10 = (xin1 && yin0) ? wgt[f] * wx1 * wy0 : 0.f;
        const float cw01 = (xin0 && yin1) ? wgt[f] * wx0 * wy1 : 0.f;
        const float cw11 = (xin1 && yin1) ? wgt[f] * wx1 * wy1 : 0.f;
        const int x0c = min(max(x0, 0), Wf - 1);
        const int x1c = min(max(x0 + 1, 0), Wf - 1);
        const int y0c = min(max(y0, 0), Hf - 1);
        const int y1c = min(max(y0 + 1, 0), Hf - 1);
        const unsigned short* row0 = vbase + (size_t)(cf + y0c * Wf) * CCH;
        const unsigned short* row1 = vbase + (size_t)(cf + y1c * Wf) * CCH;
        const u16x8 v00 = *(const u16x8*)(row0 + (size_t)x0c * CCH);
        const u16x8 v10 = *(const u16x8*)(row0 + (size_t)x1c * CCH);
        const u16x8 v01 = *(const u16x8*)(row1 + (size_t)x0c * CCH);
        const u16x8 v11 = *(const u16x8*)(row1 + (size_t)x1c * CCH);
#pragma unroll
        for (int j = 0; j < 8; ++j) {
            acc[j] += cw00 * bf2f(v00[j]) + cw10 * bf2f(v10[j])
                    + cw01 * bf2f(v01[j]) + cw11 * bf2f(v11[j]);
        }
    }

    u16x8 ov;
#pragma unroll
    for (int j = 0; j < 8; ++j) ov[j] = f2bf(acc[j]);
    *(u16x8*)(samp + ((size_t)n * TOT_S + s) * CCH + lane * 8) = ov;
}

// ---------------------------------------------------------------------------
// MFMA GEMM 3: out[n][o][s] = (sum_c Wo[o][c]*samp[s][c] + bo[o]) * scale[o]
// ---------------------------------------------------------------------------
__global__ __launch_bounds__(256)
void gemm_out_mfma(const unsigned short* __restrict__ Wob,
                   const unsigned short* __restrict__ Sampb,
                   const float* __restrict__ bo, const float* __restrict__ scale,
                   float* __restrict__ out)
{
    __shared__ unsigned short Sl[128 * PITCH];
    __shared__ unsigned short Wl[128 * PITCH];
    const int n  = blockIdx.z;
    const int ob = blockIdx.y * 128;
    const int sb = blockIdx.x * 128;
    const int tid = threadIdx.x;
    const int r   = tid >> 1;
    const int seg = (tid & 1) * 16;
    const int sr = min(sb + r, TOT_S - 1);
    const unsigned short* ssrc = Sampb + ((size_t)n * TOT_S + sr) * CCH + seg;
    const unsigned short* wsrc = Wob + ((size_t)(ob + r)) * CCH + seg;
    unsigned short* sdst = &Sl[r * PITCH + seg];
    unsigned short* wdst = &Wl[r * PITCH + seg];

    const int wave = tid >> 6, lane = tid & 63;
    const int m0 = (wave & 1) * 64, n0 = (wave >> 1) * 64;
    const int row16 = lane & 15, q = lane >> 4;

    u16x8 s0v = *(const u16x8*)(ssrc);
    u16x8 s1v = *(const u16x8*)(ssrc + 8);
    u16x8 w0v = *(const u16x8*)(wsrc);
    u16x8 w1v = *(const u16x8*)(wsrc + 8);

    f32x4 acc[4][4] = {};
    for (int k0 = 0; k0 < CCH; k0 += 32) {
        *(u16x8*)sdst = s0v; *(u16x8*)(sdst + 8) = s1v;
        *(u16x8*)wdst = w0v; *(u16x8*)(wdst + 8) = w1v;
        __syncthreads();
        if (k0 + 32 < CCH) {
            s0v = *(const u16x8*)(ssrc + k0 + 32);
            s1v = *(const u16x8*)(ssrc + k0 + 40);
            w0v = *(const u16x8*)(wsrc + k0 + 32);
            w1v = *(const u16x8*)(wsrc + k0 + 40);
        }
        short8 af[4], bfr[4];
#pragma unroll
        for (int mt = 0; mt < 4; ++mt)
            af[mt] = *(const short8*)&Sl[(m0 + mt * 16 + row16) * PITCH + q * 8];
#pragma unroll
        for (int nt = 0; nt < 4; ++nt)
            bfr[nt] = *(const short8*)&Wl[(n0 + nt * 16 + row16) * PITCH + q * 8];
#pragma unroll
        for (int mt = 0; mt < 4; ++mt)
#pragma unroll
            for (int nt = 0; nt < 4; ++nt)
                acc[mt][nt] = __builtin_amdgcn_mfma_f32_16x16x32_bf16(
                    af[mt], bfr[nt], acc[mt][nt], 0, 0, 0);
        __syncthreads();
    }

#pragma unroll
    for (int nt = 0; nt < 4; ++nt) {
        const int o = ob + n0 + nt * 16 + row16;
        const float bo_ = bo[o];
        const float sc_ = scale[o];
        float* orow = out + ((size_t)n * CCH + o) * (size_t)TOT_S;
#pragma unroll
        for (int mt = 0; mt < 4; ++mt) {
            const int s0 = sb + m0 + mt * 16 + q * 4;
            const f32x4 a = acc[mt][nt];
            if (s0 + 3 < TOT_S) {
                float2 v0 = make_float2((a[0] + bo_) * sc_, (a[1] + bo_) * sc_);
                float2 v1 = make_float2((a[2] + bo_) * sc_, (a[3] + bo_) * sc_);
                *(float2*)(orow + s0) = v0;
                *(float2*)(orow + s0 + 2) = v1;
            } else {
                for (int i = 0; i < 4; ++i)
                    if (s0 + i < TOT_S) orow[s0 + i] = (a[i] + bo_) * sc_;
            }
        }
    }
}

// ---------------------------------------------------------------------------
extern "C" void kernel_launch(void* const* d_in, const int* in_sizes, int n_in,
                              void* d_out, int out_size, void* d_ws, size_t ws_size,
                              hipStream_t stream)
{
    const float* x     = (const float*)d_in[0];
    const float* pos   = (const float*)d_in[1];
    const unsigned char* mask = (const unsigned char*)d_in[2];
    const float* vsz   = (const float*)d_in[3];
    const float* vsc   = (const float*)d_in[4];
    const float* Wv    = (const float*)d_in[5];
    const float* bv    = (const float*)d_in[6];
    const float* Wloc  = (const float*)d_in[7];
    const float* bloc  = (const float*)d_in[8];
    const float* Ww    = (const float*)d_in[9];
    const float* bw    = (const float*)d_in[10];
    const float* Wo    = (const float*)d_in[11];
    const float* bo    = (const float*)d_in[12];
    const float* scale = (const float*)d_in[13];
    float* out = (float*)d_out;

    const size_t SC = (size_t)TOT_S * CCH;
    unsigned short* valb  = (unsigned short*)d_ws;           // N*S*512 bf16
    unsigned short* sampb = valb  + 2 * SC;                  // N*S*512 bf16
    float* offw = (float*)(sampb + 2 * SC);                  // N*S*96 f32
    unsigned short* wvb = (unsigned short*)(offw + 2 * (size_t)TOT_S * 96);
    unsigned short* wob = wvb + 512 * 512;
    unsigned short* wlb = wob + 512 * 512;
    unsigned short* wwb = wlb + 64 * 512;

    cast_f32_bf16<<<256, 256, 0, stream>>>(Wv,   wvb, 512 * 512 / 4);
    cast_f32_bf16<<<256, 256, 0, stream>>>(Wo,   wob, 512 * 512 / 4);
    cast_f32_bf16<<<32,  256, 0, stream>>>(Wloc, wlb, 64 * 512 / 4);
    cast_f32_bf16<<<16,  256, 0, stream>>>(Ww,   wwb, 32 * 512 / 4);

    const int sTiles = (TOT_S + 127) / 128;  // 104

    gemm_value_mfma<<<dim3(sTiles, CCH / 128, NBATCH), 256, 0, stream>>>(
        wvb, x, bv, mask, valb);
    gemm_offw_mfma<<<dim3(sTiles, 1, NBATCH), 256, 0, stream>>>(
        wlb, wwb, bloc, bw, x, pos, mask, offw);

    const int items = NBATCH * TOT_S;
    sample_attn<<<(items + 3) / 4, dim3(64, 4), 0, stream>>>(valb, offw, vsz, vsc, sampb);

    gemm_out_mfma<<<dim3(sTiles, CCH / 128, NBATCH), 256, 0, stream>>>(
        wob, sampb, bo, scale, out);
}

// Round 6
// 327.685 us; speedup vs baseline: 1.0655x; 1.0655x over previous
//
#include <hip/hip_runtime.h>
#include <math.h>

#define TOT_S   13294
#define NBATCH  2
#define CCH     512
#define MHEAD   8
#define PITCH   40   // LDS row pitch in bf16 elems (32 + 8 pad -> 80B)

typedef short     short8  __attribute__((ext_vector_type(8)));
typedef float     f32x4   __attribute__((ext_vector_type(4)));
typedef unsigned short u16x8 __attribute__((ext_vector_type(8)));
typedef unsigned short u16x4 __attribute__((ext_vector_type(4)));

__device__ __forceinline__ unsigned short f2bf(float f) {
    union { float f; unsigned int u; } v; v.f = f;
    unsigned int r = v.u + 0x7fffu + ((v.u >> 16) & 1u);   // RNE
    return (unsigned short)(r >> 16);
}
__device__ __forceinline__ float bf2f(unsigned short h) {
    union { unsigned int u; float f; } v; v.u = ((unsigned int)h) << 16;
    return v.f;
}

// ---------------------------------------------------------------------------
// All four weight casts in ONE launch.
// quad counts: Wv 65536 | Wo 65536 | Wloc 8192 | Ww 4096  (total 143360)
// ---------------------------------------------------------------------------
__global__ void cast_weights(const float* __restrict__ Wv, const float* __restrict__ Wo,
                             const float* __restrict__ Wl, const float* __restrict__ Ww,
                             unsigned short* __restrict__ wvb, unsigned short* __restrict__ wob,
                             unsigned short* __restrict__ wlb, unsigned short* __restrict__ wwb)
{
    const int i = blockIdx.x * blockDim.x + threadIdx.x;
    const float* src; unsigned short* dst; int off;
    if      (i < 65536)  { src = Wv; dst = wvb; off = i; }
    else if (i < 131072) { src = Wo; dst = wob; off = i - 65536; }
    else if (i < 139264) { src = Wl; dst = wlb; off = i - 131072; }
    else if (i < 143360) { src = Ww; dst = wwb; off = i - 139264; }
    else return;
    const float4 v = *(const float4*)(src + (size_t)off * 4);
    u16x4 o;
    o[0] = f2bf(v.x); o[1] = f2bf(v.y); o[2] = f2bf(v.z); o[3] = f2bf(v.w);
    *(u16x4*)(dst + (size_t)off * 4) = o;
}

// ---------------------------------------------------------------------------
// LDS-tiled transpose-cast: xbt[n][s][c] = bf16(x[n][c][s]).
// Tile 64 s x 128 c. Reads coalesced 256B rows; ds_write_b128 conflict-free
// (65-bank row stride); ds_read_b128 2-way (free); writes 256B runs.
// ---------------------------------------------------------------------------
__global__ __launch_bounds__(256)
void transpose_cast(const float* __restrict__ x,
                    unsigned short* __restrict__ xbt)
{
    __shared__ unsigned short L[64 * 130];
    const int n  = blockIdx.z;
    const int sb = blockIdx.x * 64;
    const int cb = blockIdx.y * 128;
    const int tid = threadIdx.x;
    const int ls = tid & 63;
    const int cg = tid >> 6;          // 0..3 -> c chunk of 32
    const int ssafe = min(sb + ls, TOT_S - 1);
    const float* Xn = x + (size_t)n * CCH * TOT_S;

#pragma unroll
    for (int jj = 0; jj < 4; ++jj) {          // 4 groups of 8 c-rows
        u16x8 t;
#pragma unroll
        for (int j = 0; j < 8; ++j) {
            const int c = cg * 32 + jj * 8 + j;
            t[j] = f2bf(Xn[(size_t)(cb + c) * TOT_S + ssafe]);
        }
        *(u16x8*)&L[ls * 130 + cg * 32 + jj * 8] = t;
    }
    __syncthreads();

    const int lc = (tid & 15) * 8;
    const int rbase = tid >> 4;       // 0..15
#pragma unroll
    for (int rr = 0; rr < 4; ++rr) {
        const int row = rbase + rr * 16;
        const int sg = sb + row;
        if (sg < TOT_S) {
            const u16x8 v = *(const u16x8*)&L[row * 130 + lc];
            *(u16x8*)(xbt + ((size_t)n * TOT_S + sg) * CCH + cb + lc) = v;
        }
    }
}

// ---------------------------------------------------------------------------
// MFMA GEMM 1 (round-4 structure: precast bf16 B, register-prefetch, BK=32)
// ---------------------------------------------------------------------------
__global__ __launch_bounds__(256)
void gemm_value_mfma(const unsigned short* __restrict__ Wb,
                     const unsigned short* __restrict__ Act,   // xbt (N,S,512)
                     const float* __restrict__ bv,
                     const unsigned char* __restrict__ mask,
                     unsigned short* __restrict__ valb)
{
    __shared__ unsigned short Wl[128 * PITCH];
    __shared__ unsigned short Al[128 * PITCH];
    const int n  = blockIdx.z;
    const int ob = blockIdx.y * 128;
    const int sb = blockIdx.x * 128;
    const int tid = threadIdx.x;
    const int r   = tid >> 1;
    const int seg = (tid & 1) * 16;
    const unsigned short* wsrc = Wb + ((size_t)(ob + r)) * CCH + seg;
    const int sr = min(sb + r, TOT_S - 1);
    const unsigned short* asrc = Act + ((size_t)n * TOT_S + sr) * CCH + seg;
    unsigned short* wdst = &Wl[r * PITCH + seg];
    unsigned short* adst = &Al[r * PITCH + seg];

    const int wave = tid >> 6, lane = tid & 63;
    const int m0 = (wave & 1) * 64, n0 = (wave >> 1) * 64;
    const int row16 = lane & 15, q = lane >> 4;

    u16x8 w0 = *(const u16x8*)(wsrc);
    u16x8 w1 = *(const u16x8*)(wsrc + 8);
    u16x8 a0 = *(const u16x8*)(asrc);
    u16x8 a1 = *(const u16x8*)(asrc + 8);

    f32x4 acc[4][4] = {};
    for (int k0 = 0; k0 < CCH; k0 += 32) {
        *(u16x8*)wdst = w0; *(u16x8*)(wdst + 8) = w1;
        *(u16x8*)adst = a0; *(u16x8*)(adst + 8) = a1;
        __syncthreads();
        if (k0 + 32 < CCH) {
            w0 = *(const u16x8*)(wsrc + k0 + 32);
            w1 = *(const u16x8*)(wsrc + k0 + 40);
            a0 = *(const u16x8*)(asrc + k0 + 32);
            a1 = *(const u16x8*)(asrc + k0 + 40);
        }
        short8 af[4], bfr[4];
#pragma unroll
        for (int mt = 0; mt < 4; ++mt)
            af[mt] = *(const short8*)&Wl[(m0 + mt * 16 + row16) * PITCH + q * 8];
#pragma unroll
        for (int nt = 0; nt < 4; ++nt)
            bfr[nt] = *(const short8*)&Al[(n0 + nt * 16 + row16) * PITCH + q * 8];
#pragma unroll
        for (int mt = 0; mt < 4; ++mt)
#pragma unroll
            for (int nt = 0; nt < 4; ++nt)
                acc[mt][nt] = __builtin_amdgcn_mfma_f32_16x16x32_bf16(
                    af[mt], bfr[nt], acc[mt][nt], 0, 0, 0);
        __syncthreads();
    }

#pragma unroll
    for (int nt = 0; nt < 4; ++nt) {
        const int s = sb + n0 + nt * 16 + row16;
        if (s >= TOT_S) continue;
        const float msk = mask[(size_t)n * TOT_S + s] ? 0.f : 1.f;
        unsigned short* orow = valb + ((size_t)n * TOT_S + s) * CCH + ob + m0;
#pragma unroll
        for (int mt = 0; mt < 4; ++mt) {
            const f32x4 bvv = *(const f32x4*)(bv + ob + m0 + mt * 16 + q * 4);
            const f32x4 a = acc[mt][nt];
            u16x4 ov;
            ov[0] = f2bf((a[0] + bvv[0]) * msk);
            ov[1] = f2bf((a[1] + bvv[1]) * msk);
            ov[2] = f2bf((a[2] + bvv[2]) * msk);
            ov[3] = f2bf((a[3] + bvv[3]) * msk);
            *(u16x4*)(orow + mt * 16 + q * 4) = ov;
        }
    }
}

// ---------------------------------------------------------------------------
// MFMA GEMM 2 (offsets+logits) WITH fused transpose-cast of (mask?0:x+pos).
// gridDim.y == 1 -> staging executed exactly once per s-tile (no redundancy).
// ---------------------------------------------------------------------------
__global__ __launch_bounds__(256)
void gemm_offw_mfma(const unsigned short* __restrict__ Wlb,
                    const unsigned short* __restrict__ Wwb,
                    const float* __restrict__ bloc, const float* __restrict__ bw,
                    const float* __restrict__ X, const float* __restrict__ POS,
                    const unsigned char* __restrict__ mask,
                    float* __restrict__ offw)
{
    __shared__ unsigned short Wl[128 * PITCH];
    __shared__ unsigned short Al[128 * PITCH];
    const int n  = blockIdx.z;
    const int sb = blockIdx.x * 128;
    const int tid = threadIdx.x;

    const int r   = tid >> 1;
    const int seg = (tid & 1) * 16;
    const bool wzero = (r >= 96);
    const unsigned short* wsrc =
        (r < 64) ? (Wlb + (size_t)r * CCH + seg)
                 : (Wwb + (size_t)((r < 96 ? r : 95) - 64) * CCH + seg);
    unsigned short* wdst = &Wl[r * PITCH + seg];

    const int kr = tid & 7;
    const int sq = tid >> 3;
    const int sl = sq * 4;
    const int sg = sb + sl;
    const float* Xn = X   + (size_t)n * CCH * TOT_S;
    const float* Pn = POS + (size_t)n * CCH * TOT_S;
    const bool fast = (sg + 3 < TOT_S);
    float mkf[4];
#pragma unroll
    for (int i = 0; i < 4; ++i)
        mkf[i] = mask[(size_t)n * TOT_S + min(sg + i, TOT_S - 1)] ? 0.f : 1.f;

    const int wave = tid >> 6, lane = tid & 63;
    const int m0 = (wave & 1) * 64, n0 = (wave >> 1) * 64;
    const int row16 = lane & 15, q = lane >> 4;

    u16x8 w0 = {}, w1 = {};
    if (!wzero) { w0 = *(const u16x8*)(wsrc); w1 = *(const u16x8*)(wsrc + 8); }
    f32x4 xv[4];
#pragma unroll
    for (int j = 0; j < 4; ++j) {
        const size_t roff = (size_t)(kr * 4 + j) * TOT_S;
        if (fast) {
            const f32x4 a = *(const f32x4*)(Xn + roff + sg);
            const f32x4 b = *(const f32x4*)(Pn + roff + sg);
#pragma unroll
            for (int i = 0; i < 4; ++i) xv[j][i] = (a[i] + b[i]) * mkf[i];
        } else {
#pragma unroll
            for (int i = 0; i < 4; ++i) {
                const int si = min(sg + i, TOT_S - 1);
                xv[j][i] = (Xn[roff + si] + Pn[roff + si]) * mkf[i];
            }
        }
    }

    f32x4 acc[4][4] = {};
    for (int k0 = 0; k0 < CCH; k0 += 32) {
        *(u16x8*)wdst = w0; *(u16x8*)(wdst + 8) = w1;
#pragma unroll
        for (int i = 0; i < 4; ++i) {
            u16x4 t;
            t[0] = f2bf(xv[0][i]); t[1] = f2bf(xv[1][i]);
            t[2] = f2bf(xv[2][i]); t[3] = f2bf(xv[3][i]);
            *(u16x4*)&Al[(sl + i) * PITCH + kr * 4] = t;
        }
        __syncthreads();
        if (k0 + 32 < CCH) {
            if (!wzero) {
                w0 = *(const u16x8*)(wsrc + k0 + 32);
                w1 = *(const u16x8*)(wsrc + k0 + 40);
            }
#pragma unroll
            for (int j = 0; j < 4; ++j) {
                const size_t roff = (size_t)(k0 + 32 + kr * 4 + j) * TOT_S;
                if (fast) {
                    const f32x4 a = *(const f32x4*)(Xn + roff + sg);
                    const f32x4 b = *(const f32x4*)(Pn + roff + sg);
#pragma unroll
                    for (int i = 0; i < 4; ++i) xv[j][i] = (a[i] + b[i]) * mkf[i];
                } else {
#pragma unroll
                    for (int i = 0; i < 4; ++i) {
                        const int si = min(sg + i, TOT_S - 1);
                        xv[j][i] = (Xn[roff + si] + Pn[roff + si]) * mkf[i];
                    }
                }
            }
        }
        short8 af[4], bfr[4];
#pragma unroll
        for (int mt = 0; mt < 4; ++mt)
            af[mt] = *(const short8*)&Wl[(m0 + mt * 16 + row16) * PITCH + q * 8];
#pragma unroll
        for (int nt = 0; nt < 4; ++nt)
            bfr[nt] = *(const short8*)&Al[(n0 + nt * 16 + row16) * PITCH + q * 8];
#pragma unroll
        for (int mt = 0; mt < 4; ++mt)
#pragma unroll
            for (int nt = 0; nt < 4; ++nt)
                acc[mt][nt] = __builtin_amdgcn_mfma_f32_16x16x32_bf16(
                    af[mt], bfr[nt], acc[mt][nt], 0, 0, 0);
        __syncthreads();
    }

#pragma unroll
    for (int nt = 0; nt < 4; ++nt) {
        const int s = sb + n0 + nt * 16 + row16;
        if (s >= TOT_S) continue;
        float* orow = offw + ((size_t)n * TOT_S + s) * 96;
#pragma unroll
        for (int mt = 0; mt < 4; ++mt) {
            const int o = m0 + mt * 16 + q * 4;
            if (o < 96) {
                const float* bsrc = (o < 64) ? (bloc + o) : (bw + o - 64);
                const f32x4 bb = *(const f32x4*)bsrc;
                f32x4 v = acc[mt][nt];
                v[0] += bb[0]; v[1] += bb[1]; v[2] += bb[2]; v[3] += bb[3];
                *(f32x4*)(orow + o) = v;
            }
        }
    }
}

// ---------------------------------------------------------------------------
// Sampling: one wave per (n,s). lane -> head m = lane>>3, c = lane*8..+8.
// ---------------------------------------------------------------------------
__global__ __launch_bounds__(256)
void sample_attn(const unsigned short* __restrict__ value,
                 const float* __restrict__ offw,
                 const float* __restrict__ vsizes,
                 const float* __restrict__ vscales,
                 unsigned short* __restrict__ samp)
{
    const int lane = threadIdx.x;
    const int item = blockIdx.x * blockDim.y + threadIdx.y;
    const int total = NBATCH * TOT_S;
    if (item >= total) return;
    const int s = item % TOT_S;
    const int n = item / TOT_S;
    const int m = lane >> 3;

    int lvl; float prex, prey;
    if (s < 10000)      { lvl = 0; const int l = s;         const int qq = l / 100; prey = qq + 0.5f; prex = (l - qq * 100) + 0.5f; }
    else if (s < 12500) { lvl = 1; const int l = s - 10000; const int qq = l / 50;  prey = qq + 0.5f; prex = (l - qq * 50)  + 0.5f; }
    else if (s < 13125) { lvl = 2; const int l = s - 12500; const int qq = l / 25;  prey = qq + 0.5f; prex = (l - qq * 25)  + 0.5f; }
    else                { lvl = 3; const int l = s - 13125; const int qq = l / 13;  prey = qq + 0.5f; prex = (l - qq * 13)  + 0.5f; }

    const float* ow = offw + ((size_t)n * TOT_S + s) * 96;

    const float w0 = ow[64 + m * 4 + 0], w1 = ow[64 + m * 4 + 1];
    const float w2 = ow[64 + m * 4 + 2], w3 = ow[64 + m * 4 + 3];
    const float mx = fmaxf(fmaxf(w0, w1), fmaxf(w2, w3));
    const float e0 = expf(w0 - mx), e1 = expf(w1 - mx), e2 = expf(w2 - mx), e3 = expf(w3 - mx);
    const float inv = 1.f / (e0 + e1 + e2 + e3);
    const float wgt[4] = { e0 * inv, e1 * inv, e2 * inv, e3 * inv };

    const int HS[4]  = { 100, 50, 25, 13 };
    const int WS[4]  = { 100, 50, 25, 13 };
    const int CUR[4] = { 0, 10000, 12500, 13125 };

    const float invsx = 1.f / vsizes[((n * 4) + lvl) * 2 + 0];
    const float invsy = 1.f / vsizes[((n * 4) + lvl) * 2 + 1];
    const unsigned short* vbase = value + (size_t)n * TOT_S * CCH + lane * 8;

    float acc[8] = {};
#pragma unroll
    for (int f = 0; f < 4; ++f) {
        const float offx = ow[(m * 4 + f) * 2 + 0];
        const float offy = ow[(m * 4 + f) * 2 + 1];
        const float scx = 2.f * vscales[((n * 4) + f) * 2 + 0] * invsx;
        const float scy = 2.f * vscales[((n * 4) + f) * 2 + 1] * invsy;
        const int Wf = WS[f], Hf = HS[f], cf = CUR[f];
        const float xi = (offx + prex) * scx * (Wf * 0.5f) - 0.5f;
        const float yi = (offy + prey) * scy * (Hf * 0.5f) - 0.5f;
        const float x0f = floorf(xi), y0f = floorf(yi);
        const float wx1 = xi - x0f, wy1 = yi - y0f;
        const float wx0 = 1.f - wx1, wy0 = 1.f - wy1;
        const int x0 = (int)x0f, y0 = (int)y0f;
        const bool xin0 = (x0 >= 0) && (x0 < Wf);
        const bool xin1 = (x0 + 1 >= 0) && (x0 + 1 < Wf);
        const bool yin0 = (y0 >= 0) && (y0 < Hf);
        const bool yin1 = (y0 + 1 >= 0) && (y0 + 1 < Hf);
        const float cw00 = (xin0 && yin0) ? wgt[f] * wx0 * wy0 : 0.f;
        const float cw10 = (xin1 && yin0) ? wgt[f] * wx1 * wy0 : 0.f;
        const float cw01 = (xin0 && yin1) ? wgt[f] * wx0 * wy1 : 0.f;
        const float cw11 = (xin1 && yin1) ? wgt[f] * wx1 * wy1 : 0.f;
        const int x0c = min(max(x0, 0), Wf - 1);
        const int x1c = min(max(x0 + 1, 0), Wf - 1);
        const int y0c = min(max(y0, 0), Hf - 1);
        const int y1c = min(max(y0 + 1, 0), Hf - 1);
        const unsigned short* row0 = vbase + (size_t)(cf + y0c * Wf) * CCH;
        const unsigned short* row1 = vbase + (size_t)(cf + y1c * Wf) * CCH;
        const u16x8 v00 = *(const u16x8*)(row0 + (size_t)x0c * CCH);
        const u16x8 v10 = *(const u16x8*)(row0 + (size_t)x1c * CCH);
        const u16x8 v01 = *(const u16x8*)(row1 + (size_t)x0c * CCH);
        const u16x8 v11 = *(const u16x8*)(row1 + (size_t)x1c * CCH);
#pragma unroll
        for (int j = 0; j < 8; ++j) {
            acc[j] += cw00 * bf2f(v00[j]) + cw10 * bf2f(v10[j])
                    + cw01 * bf2f(v01[j]) + cw11 * bf2f(v11[j]);
        }
    }

    u16x8 ov;
#pragma unroll
    for (int j = 0; j < 8; ++j) ov[j] = f2bf(acc[j]);
    *(u16x8*)(samp + ((size_t)n * TOT_S + s) * CCH + lane * 8) = ov;
}

// ---------------------------------------------------------------------------
// MFMA GEMM 3: out[n][o][s] = (sum_c Wo[o][c]*samp[s][c] + bo[o]) * scale[o]
// ---------------------------------------------------------------------------
__global__ __launch_bounds__(256)
void gemm_out_mfma(const unsigned short* __restrict__ Wob,
                   const unsigned short* __restrict__ Sampb,
                   const float* __restrict__ bo, const float* __restrict__ scale,
                   float* __restrict__ out)
{
    __shared__ unsigned short Sl[128 * PITCH];
    __shared__ unsigned short Wl[128 * PITCH];
    const int n  = blockIdx.z;
    const int ob = blockIdx.y * 128;
    const int sb = blockIdx.x * 128;
    const int tid = threadIdx.x;
    const int r   = tid >> 1;
    const int seg = (tid & 1) * 16;
    const int sr = min(sb + r, TOT_S - 1);
    const unsigned short* ssrc = Sampb + ((size_t)n * TOT_S + sr) * CCH + seg;
    const unsigned short* wsrc = Wob + ((size_t)(ob + r)) * CCH + seg;
    unsigned short* sdst = &Sl[r * PITCH + seg];
    unsigned short* wdst = &Wl[r * PITCH + seg];

    const int wave = tid >> 6, lane = tid & 63;
    const int m0 = (wave & 1) * 64, n0 = (wave >> 1) * 64;
    const int row16 = lane & 15, q = lane >> 4;

    u16x8 s0v = *(const u16x8*)(ssrc);
    u16x8 s1v = *(const u16x8*)(ssrc + 8);
    u16x8 w0v = *(const u16x8*)(wsrc);
    u16x8 w1v = *(const u16x8*)(wsrc + 8);

    f32x4 acc[4][4] = {};
    for (int k0 = 0; k0 < CCH; k0 += 32) {
        *(u16x8*)sdst = s0v; *(u16x8*)(sdst + 8) = s1v;
        *(u16x8*)wdst = w0v; *(u16x8*)(wdst + 8) = w1v;
        __syncthreads();
        if (k0 + 32 < CCH) {
            s0v = *(const u16x8*)(ssrc + k0 + 32);
            s1v = *(const u16x8*)(ssrc + k0 + 40);
            w0v = *(const u16x8*)(wsrc + k0 + 32);
            w1v = *(const u16x8*)(wsrc + k0 + 40);
        }
        short8 af[4], bfr[4];
#pragma unroll
        for (int mt = 0; mt < 4; ++mt)
            af[mt] = *(const short8*)&Sl[(m0 + mt * 16 + row16) * PITCH + q * 8];
#pragma unroll
        for (int nt = 0; nt < 4; ++nt)
            bfr[nt] = *(const short8*)&Wl[(n0 + nt * 16 + row16) * PITCH + q * 8];
#pragma unroll
        for (int mt = 0; mt < 4; ++mt)
#pragma unroll
            for (int nt = 0; nt < 4; ++nt)
                acc[mt][nt] = __builtin_amdgcn_mfma_f32_16x16x32_bf16(
                    af[mt], bfr[nt], acc[mt][nt], 0, 0, 0);
        __syncthreads();
    }

#pragma unroll
    for (int nt = 0; nt < 4; ++nt) {
        const int o = ob + n0 + nt * 16 + row16;
        const float bo_ = bo[o];
        const float sc_ = scale[o];
        float* orow = out + ((size_t)n * CCH + o) * (size_t)TOT_S;
#pragma unroll
        for (int mt = 0; mt < 4; ++mt) {
            const int s0 = sb + m0 + mt * 16 + q * 4;
            const f32x4 a = acc[mt][nt];
            if (s0 + 3 < TOT_S) {
                float2 v0 = make_float2((a[0] + bo_) * sc_, (a[1] + bo_) * sc_);
                float2 v1 = make_float2((a[2] + bo_) * sc_, (a[3] + bo_) * sc_);
                *(float2*)(orow + s0) = v0;
                *(float2*)(orow + s0 + 2) = v1;
            } else {
                for (int i = 0; i < 4; ++i)
                    if (s0 + i < TOT_S) orow[s0 + i] = (a[i] + bo_) * sc_;
            }
        }
    }
}

// ---------------------------------------------------------------------------
extern "C" void kernel_launch(void* const* d_in, const int* in_sizes, int n_in,
                              void* d_out, int out_size, void* d_ws, size_t ws_size,
                              hipStream_t stream)
{
    const float* x     = (const float*)d_in[0];
    const float* pos   = (const float*)d_in[1];
    const unsigned char* mask = (const unsigned char*)d_in[2];
    const float* vsz   = (const float*)d_in[3];
    const float* vsc   = (const float*)d_in[4];
    const float* Wv    = (const float*)d_in[5];
    const float* bv    = (const float*)d_in[6];
    const float* Wloc  = (const float*)d_in[7];
    const float* bloc  = (const float*)d_in[8];
    const float* Ww    = (const float*)d_in[9];
    const float* bw    = (const float*)d_in[10];
    const float* Wo    = (const float*)d_in[11];
    const float* bo    = (const float*)d_in[12];
    const float* scale = (const float*)d_in[13];
    float* out = (float*)d_out;

    const size_t SC = (size_t)TOT_S * CCH;
    unsigned short* valb  = (unsigned short*)d_ws;           // N*S*512 bf16
    unsigned short* sampb = valb  + 2 * SC;                  // N*S*512 bf16
    unsigned short* xbt   = sampb + 2 * SC;                  // N*S*512 bf16
    float* offw = (float*)(xbt + 2 * SC);                    // N*S*96 f32
    unsigned short* wvb = (unsigned short*)(offw + 2 * (size_t)TOT_S * 96);
    unsigned short* wob = wvb + 512 * 512;
    unsigned short* wlb = wob + 512 * 512;
    unsigned short* wwb = wlb + 64 * 512;

    cast_weights<<<(143360 + 255) / 256, 256, 0, stream>>>(
        Wv, Wo, Wloc, Ww, wvb, wob, wlb, wwb);

    transpose_cast<<<dim3((TOT_S + 63) / 64, CCH / 128, NBATCH), 256, 0, stream>>>(
        x, xbt);

    const int sTiles = (TOT_S + 127) / 128;  // 104

    gemm_value_mfma<<<dim3(sTiles, CCH / 128, NBATCH), 256, 0, stream>>>(
        wvb, xbt, bv, mask, valb);
    gemm_offw_mfma<<<dim3(sTiles, 1, NBATCH), 256, 0, stream>>>(
        wlb, wwb, bloc, bw, x, pos, mask, offw);

    const int items = NBATCH * TOT_S;
    sample_attn<<<(items + 3) / 4, dim3(64, 4), 0, stream>>>(valb, offw, vsz, vsc, sampb);

    gemm_out_mfma<<<dim3(sTiles, CCH / 128, NBATCH), 256, 0, stream>>>(
        wob, sampb, bo, scale, out);
}